// Round 4
// baseline (339.142 us; speedup 1.0000x reference)
//
#include <hip/hip_runtime.h>

#define EPS 1e-5f
#define PSTRIDE 1120  // per-group param stride (floats): [0,512)=A, [512,1024)=sw, [1024,1096)=weff, [1096]=kc

// =================== Kernel 1: per-group stats & params ===================
// grid 1024 (one block per group), block 256. No gx LDS staging: stream from
// global twice (2nd pass L2/L3-warm). LDS ~17 KiB -> not occupancy-limiting.
__launch_bounds__(256, 4)
__global__ void k1_stats(const float* __restrict__ x,
                         const float* __restrict__ w1,
                         const float* __restrict__ b1,
                         const float* __restrict__ w3,
                         const float* __restrict__ b3,
                         const float* __restrict__ gn_w,
                         const float* __restrict__ gn_b,
                         float* __restrict__ params)
{
  __shared__ float rs[512];        // row sums [8][64]
  __shared__ float cs[512];        // col sums [8][64]
  __shared__ float sh[512];        // sigmoid row gate
  __shared__ float sw[512];        // sigmoid col gate
  __shared__ float colpart[2048];  // per-wave col partials [4][8][64]
  __shared__ float wavepart[64];   // per-wave gated p1/p2 [4][16]
  __shared__ float Ssum[8], mu_s[8], rstd_s[8], m2[8], x11[8], alpha[8];
  __shared__ float corners[32];    // [ic][4]: g00,g063,g630,g6363
  __shared__ float kc_s;

  const int t    = threadIdx.x;
  const int g    = blockIdx.x;
  const int q    = t & 15;         // column quad
  const int rg   = t >> 4;         // 0..15 row-group
  const int wv   = t >> 6;         // wave 0..3
  const int lane = t & 63;
  const float*  xg  = x + (size_t)g * 32768;
  const float4* xg4 = (const float4*)xg;

  // ---- pass 1: row sums + per-thread col partials (registers) ----
  float4 cacc[8];
#pragma unroll
  for (int c = 0; c < 8; ++c) cacc[c] = make_float4(0.f, 0.f, 0.f, 0.f);
#pragma unroll
  for (int c = 0; c < 8; ++c) {
#pragma unroll
    for (int k = 0; k < 4; ++k) {
      float4 v = xg4[c*1024 + t + 256*k];          // row i = rg+16k, quad q
      cacc[c].x += v.x; cacc[c].y += v.y; cacc[c].z += v.z; cacc[c].w += v.w;
      float rp = (v.x + v.y) + (v.z + v.w);
      rp += __shfl_xor(rp, 1, 64);
      rp += __shfl_xor(rp, 2, 64);
      rp += __shfl_xor(rp, 4, 64);
      rp += __shfl_xor(rp, 8, 64);
      if (q == 0) rs[c*64 + rg + 16*k] = rp;
    }
  }
  // reduce col partials across the 4 row-subgroups of each wave
#pragma unroll
  for (int c = 0; c < 8; ++c) {
    float sx = cacc[c].x, sy = cacc[c].y, sz = cacc[c].z, sww = cacc[c].w;
    sx += __shfl_xor(sx, 16, 64); sx += __shfl_xor(sx, 32, 64);
    sy += __shfl_xor(sy, 16, 64); sy += __shfl_xor(sy, 32, 64);
    sz += __shfl_xor(sz, 16, 64); sz += __shfl_xor(sz, 32, 64);
    sww += __shfl_xor(sww, 16, 64); sww += __shfl_xor(sww, 32, 64);
    if (lane < 16) *(float4*)&colpart[wv*512 + c*64 + lane*4] = make_float4(sx, sy, sz, sww);
  }
  __syncthreads();

  // ---- finalize col sums, channel totals, corner loads ----
#pragma unroll
  for (int r = 0; r < 2; ++r) {
    int idx = t + 256*r;
    cs[idx] = colpart[idx] + colpart[512 + idx] + colpart[1024 + idx] + colpart[1536 + idx];
  }
  if (t < 8) {
    float S = 0.f;
    for (int i = 0; i < 64; ++i) S += rs[t*64 + i];
    Ssum[t] = S;
  }
  if (t >= 32 && t < 64) {
    int ic = (t - 32) >> 2, cr = t & 3;
    int ofs = (cr == 0) ? 0 : (cr == 1) ? 63 : (cr == 2) ? 63*64 : 4095;
    corners[t - 32] = xg[ic*4096 + ofs];
  }
  __syncthreads();

  // ---- gates sh/sw: 8x8 matvec on row/col means + sigmoid ----
#pragma unroll
  for (int r = 0; r < 2; ++r) {
    int idx = t + 256*r;           // 0..511
    int o = idx >> 6, i = idx & 63;
    float a1 = b1[o], a2 = a1;
#pragma unroll
    for (int c = 0; c < 8; ++c) {
      float wv1 = w1[o*8 + c];
      a1 = fmaf(wv1, rs[c*64 + i] * (1.f/64.f), a1);
      a2 = fmaf(wv1, cs[c*64 + i] * (1.f/64.f), a2);
    }
    sh[idx] = 1.f / (1.f + __expf(-a1));
    sw[idx] = 1.f / (1.f + __expf(-a2));
  }
  __syncthreads();

  // ---- pass 2: gated = gx*sh*sw sum/sumsq (re-read global, L2/L3-warm) ----
  float p1[8], p2[8];
#pragma unroll
  for (int c = 0; c < 8; ++c) { p1[c] = 0.f; p2[c] = 0.f; }
#pragma unroll
  for (int c = 0; c < 8; ++c) {
    const float4 sw4 = *(const float4*)&sw[c*64 + q*4];
#pragma unroll
    for (int k = 0; k < 4; ++k) {
      int i = rg + 16*k;
      float4 v = xg4[c*1024 + t + 256*k];
      float shv = sh[c*64 + i];
      float g0 = v.x*shv*sw4.x, g1 = v.y*shv*sw4.y;
      float g2 = v.z*shv*sw4.z, g3 = v.w*shv*sw4.w;
      p1[c] += (g0 + g1) + (g2 + g3);
      p2[c] += (g0*g0 + g1*g1) + (g2*g2 + g3*g3);
    }
  }
#pragma unroll
  for (int c = 0; c < 8; ++c) {
#pragma unroll
    for (int off = 1; off < 64; off <<= 1) {
      p1[c] += __shfl_xor(p1[c], off, 64);
      p2[c] += __shfl_xor(p2[c], off, 64);
    }
    if (lane == 0) { wavepart[wv*16 + c] = p1[c]; wavepart[wv*16 + 8 + c] = p2[c]; }
  }
  __syncthreads();

  // ---- mu/rstd (t<8) and conv-mean logits m2 (t 64..71) in parallel ----
  if (t < 8) {
    float s1 = wavepart[t]     + wavepart[16 + t] + wavepart[32 + t] + wavepart[48 + t];
    float s2 = wavepart[8 + t] + wavepart[24 + t] + wavepart[40 + t] + wavepart[56 + t];
    float mu  = s1 * (1.f/4096.f);
    float var = s2 * (1.f/4096.f) - mu*mu;
    mu_s[t]   = mu;
    rstd_s[t] = rsqrtf(var + EPS);
  } else if (t >= 64 && t < 72) {
    int o = t - 64;
    float acc = 0.f;
    for (int ic = 0; ic < 8; ++ic) {
      float S   = Ssum[ic];
      float r0  = rs[ic*64 + 0],  r63 = rs[ic*64 + 63];
      float c0  = cs[ic*64 + 0],  c63 = cs[ic*64 + 63];
      float g00   = corners[ic*4 + 0];
      float g063  = corners[ic*4 + 1];
      float g630  = corners[ic*4 + 2];
      float g6363 = corners[ic*4 + 3];
      const float* w3p = w3 + (o*8 + ic)*9;
#pragma unroll
      for (int kh = 0; kh < 3; ++kh) {
        float rex = (kh == 0) ? r63 : (kh == 2) ? r0 : 0.f;
#pragma unroll
        for (int kw = 0; kw < 3; ++kw) {
          float cex = (kw == 0) ? c63 : (kw == 2) ? c0 : 0.f;
          float corner = 0.f;
          if      (kh == 0 && kw == 0) corner = g6363;
          else if (kh == 0 && kw == 2) corner = g630;
          else if (kh == 2 && kw == 0) corner = g063;
          else if (kh == 2 && kw == 2) corner = g00;
          acc = fmaf(w3p[kh*3 + kw], (S - rex - cex) + corner, acc);
        }
      }
    }
    m2[o] = b3[o] + acc * (1.f/4096.f);
  }
  __syncthreads();

  // ---- softmaxes + scalar constants ----
  if (t == 0) {
    float e[8];
    float m = m2[0];
    for (int c = 1; c < 8; ++c) m = fmaxf(m, m2[c]);
    float ssum = 0.f;
    for (int c = 0; c < 8; ++c) { e[c] = __expf(m2[c] - m); ssum += e[c]; }
    float kc = 0.f;
    for (int c = 0; c < 8; ++c) {
      float x21 = e[c] / ssum;
      alpha[c] = x21 * gn_w[c] * rstd_s[c];
      kc += x21 * (gn_b[c] - gn_w[c] * rstd_s[c] * mu_s[c]);
    }
    // x1 channel means are exactly gn_b -> x11 = softmax(gn_b)
    float m1 = gn_b[0];
    for (int c = 1; c < 8; ++c) m1 = fmaxf(m1, gn_b[c]);
    float s1 = 0.f;
    for (int c = 0; c < 8; ++c) { e[c] = __expf(gn_b[c] - m1); s1 += e[c]; }
    for (int c = 0; c < 8; ++c) {
      float v = e[c] / s1;
      x11[c] = v;
      kc = fmaf(v, b3[c], kc);     // fold sum(x11*b3) into constant
    }
    kc_s = kc;
  }
  __syncthreads();

  // ---- write params: A = alpha*sh, sw, weff, kc ----
  float* P = params + (size_t)g * PSTRIDE;
#pragma unroll
  for (int r = 0; r < 2; ++r) {
    int idx = t + 256*r;
    int c = idx >> 6;
    P[idx]       = alpha[c] * sh[idx];
    P[512 + idx] = sw[idx];
  }
  if (t < 72) {
    float acc = 0.f;
#pragma unroll
    for (int o = 0; o < 8; ++o) acc = fmaf(x11[o], w3[o*72 + t], acc);
    P[1024 + t] = acc;
  }
  if (t == 128) P[1096] = kc_s;
}

// =================== Kernel 2: conv + gate + sigmoid + output ===================
// grid 4096 (4 row-tiles per group), block 256. LDS tile [8][18][64] = 36 KiB
// + params ~2.6 KiB -> 4 blocks/CU. Edge taps via shfl (no LDS bank conflicts).
__launch_bounds__(256, 4)
__global__ void k2_out(const float* __restrict__ x,
                       const float* __restrict__ params,
                       float* __restrict__ out)
{
  __shared__ float tile[8*18*64];  // [c][r][j], r = global row - (r0-1)
  __shared__ float pA[128];        // A[c][il] for this tile's 16 rows
  __shared__ float psw[512];       // sw[c][j]
  __shared__ float pwf[72];        // weff[ic][kh][kw]
  __shared__ float pkc;

  const int t    = threadIdx.x;
  const int g    = blockIdx.x >> 2;
  const int tl   = blockIdx.x & 3;
  const int r0   = tl << 4;
  const int lane = t & 63;
  const float4* xg4 = (const float4*)(x + (size_t)g * 32768);
  float*        og  = out + (size_t)g * 32768;
  const float*  P   = params + (size_t)g * PSTRIDE;

  // ---- stage tile (18 rows incl. halo; zeros outside [0,63]) ----
#pragma unroll
  for (int k = 0; k < 9; ++k) {
    int f   = t + 256*k;           // 0..2303
    int c   = f / 288;             // 18*16
    int rem = f - c*288;
    int r   = rem >> 4;            // 0..17
    int qq  = rem & 15;
    int row = r0 + r - 1;
    float4 v = make_float4(0.f, 0.f, 0.f, 0.f);
    if (row >= 0 && row <= 63) v = xg4[c*1024 + row*16 + qq];
    *(float4*)&tile[c*1152 + r*64 + (qq << 2)] = v;
  }
  // ---- stage params ----
  if (t < 128) pA[t] = P[(t >> 4)*64 + r0 + (t & 15)];
#pragma unroll
  for (int r = 0; r < 2; ++r) { int idx = t + 256*r; psw[idx] = P[512 + idx]; }
  if (t < 72)  pwf[t] = P[1024 + t];
  if (t == 200) pkc = P[1096];
  __syncthreads();

  // ---- fused conv + gating + sigmoid + store ----
  const int il = t >> 4;           // local row 0..15
  const int lx = t & 15;           // quad 0..15
  const int j4 = lx << 2;
  const int i  = r0 + il;

  float y0 = pkc, y1 = pkc, y2 = pkc, y3 = pkc;
#pragma unroll
  for (int ic = 0; ic < 8; ++ic) {
    const float* cb = &tile[ic*1152];
    float4 cen;
#pragma unroll
    for (int kh = 0; kh < 3; ++kh) {
      const float* rbase = cb + (il + kh)*64;
      float4 c4 = *(const float4*)(rbase + j4);
      float lv = __shfl_up(c4.w, 1, 64);    // col j4-1 (lane-1's .w)
      float rv = __shfl_down(c4.x, 1, 64);  // col j4+4 (lane+1's .x)
      if (lx == 0)  lv = 0.f;
      if (lx == 15) rv = 0.f;
      const float w0  = pwf[ic*9 + kh*3 + 0];
      const float w1v = pwf[ic*9 + kh*3 + 1];
      const float w2  = pwf[ic*9 + kh*3 + 2];
      y0 = fmaf(w0, lv,   fmaf(w1v, c4.x, fmaf(w2, c4.y, y0)));
      y1 = fmaf(w0, c4.x, fmaf(w1v, c4.y, fmaf(w2, c4.z, y1)));
      y2 = fmaf(w0, c4.y, fmaf(w1v, c4.z, fmaf(w2, c4.w, y2)));
      y3 = fmaf(w0, c4.z, fmaf(w1v, c4.w, fmaf(w2, rv,  y3)));
      if (kh == 1) cen = c4;
    }
    const float sg   = pA[ic*16 + il];
    const float4 sw4 = *(const float4*)&psw[ic*64 + j4];
    y0 = fmaf(sg * sw4.x, cen.x, y0);
    y1 = fmaf(sg * sw4.y, cen.y, y1);
    y2 = fmaf(sg * sw4.z, cen.z, y2);
    y3 = fmaf(sg * sw4.w, cen.w, y3);
  }
  const float wg0 = 1.f / (1.f + __expf(-y0));
  const float wg1 = 1.f / (1.f + __expf(-y1));
  const float wg2 = 1.f / (1.f + __expf(-y2));
  const float wg3 = 1.f / (1.f + __expf(-y3));
#pragma unroll
  for (int c = 0; c < 8; ++c) {
    const float4 cen = *(const float4*)&tile[c*1152 + (il + 1)*64 + j4];
    float4 o4;
    o4.x = cen.x * wg0;
    o4.y = cen.y * wg1;
    o4.z = cen.z * wg2;
    o4.w = cen.w * wg3;
    *(float4*)&og[c*4096 + i*64 + j4] = o4;
  }
}

extern "C" void kernel_launch(void* const* d_in, const int* in_sizes, int n_in,
                              void* d_out, int out_size, void* d_ws, size_t ws_size,
                              hipStream_t stream) {
  (void)in_sizes; (void)n_in; (void)out_size; (void)ws_size;
  const float* x    = (const float*)d_in[0];
  const float* w1   = (const float*)d_in[1];
  const float* b1   = (const float*)d_in[2];
  const float* w3   = (const float*)d_in[3];
  const float* b3   = (const float*)d_in[4];
  const float* gn_w = (const float*)d_in[5];
  const float* gn_b = (const float*)d_in[6];
  float* out    = (float*)d_out;
  float* params = (float*)d_ws;   // needs 1024*1120*4 = 4.59 MB of scratch

  k1_stats<<<1024, 256, 0, stream>>>(x, w1, b1, w3, b3, gn_w, gn_b, params);
  k2_out  <<<4096, 256, 0, stream>>>(x, params, out);
}

// Round 6
// 285.892 us; speedup vs baseline: 1.1863x; 1.1863x over previous
//
#include <hip/hip_runtime.h>

#define EPS 1e-5f
#define PSTRIDE 1120  // per-group param floats: [0,512)=A, [512,1024)=sw, [1024,1096)=weff, [1096]=kc

// =================== Kernel 1: per-group stats & params (single-pass) ===================
// grid 1024, block 512 (8 waves). Wave w holds channel w entirely in registers
// (16 float4/lane). x is read from global EXACTLY ONCE. All reductions via
// shfl + tiny LDS. ~8.6 KiB LDS. __launch_bounds__(512,4) -> <=128 VGPR.
__launch_bounds__(512, 4)
__global__ void k1_stats(const float* __restrict__ x,
                         const float* __restrict__ w1,
                         const float* __restrict__ b1,
                         const float* __restrict__ w3,
                         const float* __restrict__ b3,
                         const float* __restrict__ gn_w,
                         const float* __restrict__ gn_b,
                         float* __restrict__ params)
{
  __shared__ float rs[512];        // row sums [8][64]
  __shared__ float cs[512];        // col sums [8][64]
  __shared__ float sh[512];        // sigmoid row gate
  __shared__ float sw[512];        // sigmoid col gate
  __shared__ float Ssum[8], mu_s[8], rstd_s[8], m2[8], x11[8], alpha[8];
  __shared__ float corners[32];    // [ic][4]: g00,g063,g630,g6363
  __shared__ float kc_s;

  const int t = threadIdx.x;
  const int w = t >> 6;            // wave id == channel id (0..7)
  const int l = t & 63;
  const int s = l >> 4;            // row sub-group 0..3
  const int q = l & 15;            // column quad 0..15
  const int g = blockIdx.x;
  const float4* xg4 = (const float4*)(x + (size_t)g * 32768);

  // ---- load channel w into registers: lane l, reg k -> row s+4k, cols 4q..4q+3 ----
  float4 d[16];
#pragma unroll
  for (int k = 0; k < 16; ++k) d[k] = xg4[w*1024 + l + 64*k];

  // ---- row sums (reduce across the 16 q-lanes of each s-group) ----
#pragma unroll
  for (int k = 0; k < 16; ++k) {
    float rp = (d[k].x + d[k].y) + (d[k].z + d[k].w);
    rp += __shfl_xor(rp, 1, 64);
    rp += __shfl_xor(rp, 2, 64);
    rp += __shfl_xor(rp, 4, 64);
    rp += __shfl_xor(rp, 8, 64);
    if (q == 0) rs[w*64 + s + 4*k] = rp;
  }

  // ---- col sums (accumulate own 16 rows, reduce across the 4 s-groups) ----
  float4 cacc = make_float4(0.f, 0.f, 0.f, 0.f);
#pragma unroll
  for (int k = 0; k < 16; ++k) {
    cacc.x += d[k].x; cacc.y += d[k].y; cacc.z += d[k].z; cacc.w += d[k].w;
  }
  cacc.x += __shfl_xor(cacc.x, 16, 64); cacc.x += __shfl_xor(cacc.x, 32, 64);
  cacc.y += __shfl_xor(cacc.y, 16, 64); cacc.y += __shfl_xor(cacc.y, 32, 64);
  cacc.z += __shfl_xor(cacc.z, 16, 64); cacc.z += __shfl_xor(cacc.z, 32, 64);
  cacc.w += __shfl_xor(cacc.w, 16, 64); cacc.w += __shfl_xor(cacc.w, 32, 64);
  if (l < 16) *(float4*)&cs[w*64 + l*4] = cacc;

  // ---- channel total (sum of reduced col sums across the 16 q-lanes) ----
  float tsum = (cacc.x + cacc.y) + (cacc.z + cacc.w);
  tsum += __shfl_xor(tsum, 1, 64);
  tsum += __shfl_xor(tsum, 2, 64);
  tsum += __shfl_xor(tsum, 4, 64);
  tsum += __shfl_xor(tsum, 8, 64);
  if (l == 0) Ssum[w] = tsum;

  // ---- corners of channel w from registers ----
  if (l == 0)  corners[w*4 + 0] = d[0].x;    // gx[w][0][0]
  if (l == 15) corners[w*4 + 1] = d[0].w;    // gx[w][0][63]
  if (l == 48) corners[w*4 + 2] = d[15].x;   // gx[w][63][0]
  if (l == 63) corners[w*4 + 3] = d[15].w;   // gx[w][63][63]
  __syncthreads();

  // ---- gates sh/sw: 8x8 matvec on row/col means + sigmoid (thread t = (o=w, i=l)) ----
  {
    float a1 = b1[w], a2 = a1;
#pragma unroll
    for (int c = 0; c < 8; ++c) {
      float wv1 = w1[w*8 + c];                 // wave-uniform -> scalar load
      a1 = fmaf(wv1, rs[c*64 + l] * (1.f/64.f), a1);
      a2 = fmaf(wv1, cs[c*64 + l] * (1.f/64.f), a2);
    }
    sh[t] = 1.f / (1.f + __expf(-a1));
    sw[t] = 1.f / (1.f + __expf(-a2));
  }
  __syncthreads();

  // ---- gated = gx*sh*sw sum/sumsq from REGISTERS (no re-read) ----
  {
    const float4 sw4 = *(const float4*)&sw[w*64 + q*4];
    float p1 = 0.f, p2 = 0.f;
#pragma unroll
    for (int k = 0; k < 16; ++k) {
      const float shv = sh[w*64 + s + 4*k];
      float g0 = d[k].x * shv * sw4.x;
      float g1 = d[k].y * shv * sw4.y;
      float g2 = d[k].z * shv * sw4.z;
      float g3 = d[k].w * shv * sw4.w;
      p1 += (g0 + g1) + (g2 + g3);
      p2 += (g0*g0 + g1*g1) + (g2*g2 + g3*g3);
    }
#pragma unroll
    for (int off = 1; off < 64; off <<= 1) {
      p1 += __shfl_xor(p1, off, 64);
      p2 += __shfl_xor(p2, off, 64);
    }
    if (l == 0) {
      float mu  = p1 * (1.f/4096.f);
      float var = p2 * (1.f/4096.f) - mu*mu;
      mu_s[w]   = mu;
      rstd_s[w] = rsqrtf(var + EPS);
    }
  }

  // ---- conv-mean logits m2 (threads 64..71; needs only pre-gate LDS data) ----
  if (t >= 64 && t < 72) {
    int o = t - 64;
    float acc = 0.f;
    for (int ic = 0; ic < 8; ++ic) {
      float S   = Ssum[ic];
      float r0  = rs[ic*64 + 0],  r63 = rs[ic*64 + 63];
      float c0  = cs[ic*64 + 0],  c63 = cs[ic*64 + 63];
      float g00   = corners[ic*4 + 0];
      float g063  = corners[ic*4 + 1];
      float g630  = corners[ic*4 + 2];
      float g6363 = corners[ic*4 + 3];
      const float* w3p = w3 + (o*8 + ic)*9;
#pragma unroll
      for (int kh = 0; kh < 3; ++kh) {
        float rex = (kh == 0) ? r63 : (kh == 2) ? r0 : 0.f;
#pragma unroll
        for (int kw = 0; kw < 3; ++kw) {
          float cex = (kw == 0) ? c63 : (kw == 2) ? c0 : 0.f;
          float corner = 0.f;
          if      (kh == 0 && kw == 0) corner = g6363;
          else if (kh == 0 && kw == 2) corner = g630;
          else if (kh == 2 && kw == 0) corner = g063;
          else if (kh == 2 && kw == 2) corner = g00;
          acc = fmaf(w3p[kh*3 + kw], (S - rex - cex) + corner, acc);
        }
      }
    }
    m2[o] = b3[o] + acc * (1.f/4096.f);
  }
  __syncthreads();

  // ---- softmaxes + scalar constants ----
  if (t == 0) {
    float e[8];
    float m = m2[0];
    for (int c = 1; c < 8; ++c) m = fmaxf(m, m2[c]);
    float ssum = 0.f;
    for (int c = 0; c < 8; ++c) { e[c] = __expf(m2[c] - m); ssum += e[c]; }
    float kc = 0.f;
    for (int c = 0; c < 8; ++c) {
      float x21 = e[c] / ssum;
      alpha[c] = x21 * gn_w[c] * rstd_s[c];
      kc += x21 * (gn_b[c] - gn_w[c] * rstd_s[c] * mu_s[c]);
    }
    // x1 channel means are exactly gn_b -> x11 = softmax(gn_b)
    float m1 = gn_b[0];
    for (int c = 1; c < 8; ++c) m1 = fmaxf(m1, gn_b[c]);
    float s1 = 0.f;
    for (int c = 0; c < 8; ++c) { e[c] = __expf(gn_b[c] - m1); s1 += e[c]; }
    for (int c = 0; c < 8; ++c) {
      float v = e[c] / s1;
      x11[c] = v;
      kc = fmaf(v, b3[c], kc);     // fold sum(x11*b3) into constant
    }
    kc_s = kc;
  }
  __syncthreads();

  // ---- write params: A = alpha*sh, sw, weff, kc ----
  float* P = params + (size_t)g * PSTRIDE;
  P[t]       = alpha[w] * sh[t];
  P[512 + t] = sw[t];
  if (t < 72) {
    float acc = 0.f;
#pragma unroll
    for (int o = 0; o < 8; ++o) acc = fmaf(x11[o], w3[o*72 + t], acc);
    P[1024 + t] = acc;
  }
  if (t == 128) P[1096] = kc_s;
}

// =================== Kernel 2: conv + gate + sigmoid + output (UNCHANGED) ===================
// grid 4096 (4 row-tiles per group), block 256. LDS tile [8][18][64] = 36 KiB
// + params ~2.6 KiB -> 4 blocks/CU. Edge taps via shfl (no LDS bank conflicts).
__launch_bounds__(256, 4)
__global__ void k2_out(const float* __restrict__ x,
                       const float* __restrict__ params,
                       float* __restrict__ out)
{
  __shared__ float tile[8*18*64];  // [c][r][j], r = global row - (r0-1)
  __shared__ float pA[128];        // A[c][il] for this tile's 16 rows
  __shared__ float psw[512];       // sw[c][j]
  __shared__ float pwf[72];        // weff[ic][kh][kw]
  __shared__ float pkc;

  const int t    = threadIdx.x;
  const int g    = blockIdx.x >> 2;
  const int tl   = blockIdx.x & 3;
  const int r0   = tl << 4;
  const float4* xg4 = (const float4*)(x + (size_t)g * 32768);
  float*        og  = out + (size_t)g * 32768;
  const float*  P   = params + (size_t)g * PSTRIDE;

  // ---- stage tile (18 rows incl. halo; zeros outside [0,63]) ----
#pragma unroll
  for (int k = 0; k < 9; ++k) {
    int f   = t + 256*k;           // 0..2303
    int c   = f / 288;             // 18*16
    int rem = f - c*288;
    int r   = rem >> 4;            // 0..17
    int qq  = rem & 15;
    int row = r0 + r - 1;
    float4 v = make_float4(0.f, 0.f, 0.f, 0.f);
    if (row >= 0 && row <= 63) v = xg4[c*1024 + row*16 + qq];
    *(float4*)&tile[c*1152 + r*64 + (qq << 2)] = v;
  }
  // ---- stage params ----
  if (t < 128) pA[t] = P[(t >> 4)*64 + r0 + (t & 15)];
#pragma unroll
  for (int r = 0; r < 2; ++r) { int idx = t + 256*r; psw[idx] = P[512 + idx]; }
  if (t < 72)  pwf[t] = P[1024 + t];
  if (t == 200) pkc = P[1096];
  __syncthreads();

  // ---- fused conv + gating + sigmoid + store ----
  const int il = t >> 4;           // local row 0..15
  const int lx = t & 15;           // quad 0..15
  const int j4 = lx << 2;
  const int i  = r0 + il;

  float y0 = pkc, y1 = pkc, y2 = pkc, y3 = pkc;
#pragma unroll
  for (int ic = 0; ic < 8; ++ic) {
    const float* cb = &tile[ic*1152];
    float4 cen;
#pragma unroll
    for (int kh = 0; kh < 3; ++kh) {
      const float* rbase = cb + (il + kh)*64;
      float4 c4 = *(const float4*)(rbase + j4);
      float lv = __shfl_up(c4.w, 1, 64);    // col j4-1 (lane-1's .w)
      float rv = __shfl_down(c4.x, 1, 64);  // col j4+4 (lane+1's .x)
      if (lx == 0)  lv = 0.f;
      if (lx == 15) rv = 0.f;
      const float w0  = pwf[ic*9 + kh*3 + 0];
      const float w1v = pwf[ic*9 + kh*3 + 1];
      const float w2  = pwf[ic*9 + kh*3 + 2];
      y0 = fmaf(w0, lv,   fmaf(w1v, c4.x, fmaf(w2, c4.y, y0)));
      y1 = fmaf(w0, c4.x, fmaf(w1v, c4.y, fmaf(w2, c4.z, y1)));
      y2 = fmaf(w0, c4.y, fmaf(w1v, c4.z, fmaf(w2, c4.w, y2)));
      y3 = fmaf(w0, c4.z, fmaf(w1v, c4.w, fmaf(w2, rv,  y3)));
      if (kh == 1) cen = c4;
    }
    const float sg   = pA[ic*16 + il];
    const float4 sw4 = *(const float4*)&psw[ic*64 + j4];
    y0 = fmaf(sg * sw4.x, cen.x, y0);
    y1 = fmaf(sg * sw4.y, cen.y, y1);
    y2 = fmaf(sg * sw4.z, cen.z, y2);
    y3 = fmaf(sg * sw4.w, cen.w, y3);
  }
  const float wg0 = 1.f / (1.f + __expf(-y0));
  const float wg1 = 1.f / (1.f + __expf(-y1));
  const float wg2 = 1.f / (1.f + __expf(-y2));
  const float wg3 = 1.f / (1.f + __expf(-y3));
#pragma unroll
  for (int c = 0; c < 8; ++c) {
    const float4 cen = *(const float4*)&tile[c*1152 + (il + 1)*64 + j4];
    float4 o4;
    o4.x = cen.x * wg0;
    o4.y = cen.y * wg1;
    o4.z = cen.z * wg2;
    o4.w = cen.w * wg3;
    *(float4*)&og[c*4096 + i*64 + j4] = o4;
  }
}

extern "C" void kernel_launch(void* const* d_in, const int* in_sizes, int n_in,
                              void* d_out, int out_size, void* d_ws, size_t ws_size,
                              hipStream_t stream) {
  (void)in_sizes; (void)n_in; (void)out_size; (void)ws_size;
  const float* x    = (const float*)d_in[0];
  const float* w1   = (const float*)d_in[1];
  const float* b1   = (const float*)d_in[2];
  const float* w3   = (const float*)d_in[3];
  const float* b3   = (const float*)d_in[4];
  const float* gn_w = (const float*)d_in[5];
  const float* gn_b = (const float*)d_in[6];
  float* out    = (float*)d_out;
  float* params = (float*)d_ws;   // needs 1024*1120*4 = 4.59 MB of scratch

  k1_stats<<<1024, 512, 0, stream>>>(x, w1, b1, w3, b3, gn_w, gn_b, params);
  k2_out  <<<4096, 256, 0, stream>>>(x, params, out);
}